// Round 1
// baseline (378.897 us; speedup 1.0000x reference)
//
#include <hip/hip_runtime.h>
#include <math.h>

// MatchingLayer (BiMPM-style) — MI355X fp32 implementation.
// Shapes: B=32, L=128 (Lp=Lh), H=100, P=20, C=105 output channels per side.
// Round 0: correctness-first fp32 pipeline. Dominant cost: k_pair (2.1 G MAC).

namespace {
constexpr int B = 32;
constexpr int L = 128;
constexpr int H = 100;
constexpr int P = 20;
constexpr int C = 105;   // 1+1+1+20+20+20+1+20+1+20
constexpr float EPSF = 1e-8f;
constexpr float MINV = -1e7f;
}

// ---------------------------------------------------------------- k_prep
// grid (L, B), block 128. One block per (b,row): write masked vector,
// plain norm, and P w1-weighted norms (norm of w1[p] * v).
__global__ void k_prep(const float* __restrict__ ctx, const int* __restrict__ mask,
                       const float* __restrict__ w1,
                       float* __restrict__ dst, float* __restrict__ nrm,
                       float* __restrict__ nw)
{
    const int b = blockIdx.y, i = blockIdx.x, t = threadIdx.x;
    const int row = b * L + i;
    __shared__ float sv2[H];
    const float m = (float)mask[row];
    if (t < H) {
        float v = ctx[row * H + t] * m;
        dst[row * H + t] = v;
        sv2[t] = v * v;
    }
    __syncthreads();
    if (t < P) {
        float acc = 0.f;
        #pragma unroll 4
        for (int k = 0; k < H; ++k) { float w = w1[t * H + k]; acc += w * w * sv2[k]; }
        nw[row * P + t] = sqrtf(acc);
    } else if (t == P) {
        float acc = 0.f;
        for (int k = 0; k < H; ++k) acc += sv2[k];
        nrm[row] = sqrtf(acc);
    }
}

// ---------------------------------------------------------------- k_last
// grid B, block 128. idx = max(sum(mask)-1, 0); copy last masked vectors.
__global__ void k_last(const int* __restrict__ mask_p, const int* __restrict__ mask_h,
                       const float* __restrict__ cp, const float* __restrict__ ch,
                       float* __restrict__ cpl, float* __restrict__ chl)
{
    const int b = blockIdx.x, t = threadIdx.x;
    __shared__ int sidx[2];
    if (t == 0) {
        int s = 0;
        for (int j = 0; j < L; ++j) s += mask_p[b * L + j];
        sidx[0] = (s - 1 > 0) ? (s - 1) : 0;
        s = 0;
        for (int j = 0; j < L; ++j) s += mask_h[b * L + j];
        sidx[1] = (s - 1 > 0) ? (s - 1) : 0;
    }
    __syncthreads();
    if (t < H) {
        cpl[b * H + t] = cp[(b * L + sidx[0]) * H + t];
        chl[b * H + t] = ch[(b * L + sidx[1]) * H + t];
    }
}

// ---------------------------------------------------------------- k_cos
// grid (L, B), block 128. cos[i][j] = dot / max(n_p[i]*n_h[j], eps).
// Also writes the transpose for the h-side row-major passes.
__global__ void k_cos(const float* __restrict__ cp, const float* __restrict__ ch,
                      const float* __restrict__ np_, const float* __restrict__ nh_,
                      float* __restrict__ cosM, float* __restrict__ cosT)
{
    const int b = blockIdx.y, i = blockIdx.x, t = threadIdx.x;
    __shared__ float sa[H];
    if (t < H) sa[t] = cp[(b * L + i) * H + t];
    __syncthreads();
    const int j = t;  // blockDim == L
    const float* bv = ch + (b * L + j) * H;
    float dot = 0.f;
    #pragma unroll 4
    for (int k = 0; k < H; ++k) dot += sa[k] * bv[k];
    float c = dot / fmaxf(np_[b * L + i] * nh_[b * L + j], EPSF);
    cosM[(b * L + i) * L + j] = c;
    cosT[(b * L + j) * L + i] = c;
}

// ---------------------------------------------------------------- k_side
// grid (L, B), block 128. Generic over side (p: A=cp,Bv=ch,cosR=cos;
// h: A=ch,Bv=cp,cosR=cosT). Produces channels 0,1,2,3..22,63,64..83,84,85..104.
__global__ void k_side(const float* __restrict__ A, const float* __restrict__ Bv,
                       const float* __restrict__ cosR,
                       const int* __restrict__ maskA, const int* __restrict__ maskB,
                       const float* __restrict__ lastV,
                       const float* __restrict__ w0, const float* __restrict__ w2,
                       const float* __restrict__ w3,
                       float* __restrict__ out)
{
    const int b = blockIdx.y, i = blockIdx.x, t = threadIdx.x;
    __shared__ float sa[H], sl[H], sam[H], sax[H];
    __shared__ float scos[L], smb[L];
    __shared__ float s_cosmax, s_cosmean, s_sumcos, s_mmax;
    const float mA = (float)maskA[b * L + i];
    if (t < H) {
        sa[t] = A[(b * L + i) * H + t];
        sl[t] = lastV[b * H + t];
    }
    scos[t] = cosR[(b * L + i) * L + t];
    smb[t] = mA * (float)maskB[b * L + t];
    __syncthreads();

    if (t == 0) {
        float sc = 0.f, sm = 0.f, cnt = 0.f, mm = 0.f, vmax = MINV;
        for (int j = 0; j < L; ++j) {
            float cj = scos[j], mb = smb[j];
            sc += cj;
            sm += cj * mb;
            cnt += mb;
            mm = fmaxf(mm, mb);
            if (mb > 0.f) vmax = fmaxf(vmax, cj);
        }
        s_sumcos = sc;
        s_mmax = mm;
        s_cosmax = vmax * mm;                 // MIN_VAL*0 -> -0.0 matches ref
        s_cosmean = sm / fmaxf(cnt, EPSF);
    }
    __syncthreads();

    // attentive mean (all j, signed-max denominator) + masked attentive max
    if (t < H) {
        float am = 0.f, ax = MINV;
        for (int j = 0; j < L; ++j) {
            float bv = Bv[(b * L + j) * H + t];
            float v = scos[j] * bv;
            am += v;
            if (smb[j] > 0.f) ax = fmaxf(ax, v);
        }
        sam[t] = am / fmaxf(s_sumcos, EPSF);
        sax[t] = ax * s_mmax;
    }
    __syncthreads();

    float* orow = out + (b * L + i) * C;
    if (t < P) {                               // fP: w0 vs last
        float d = 0.f, na = 0.f, nb = 0.f;
        for (int k = 0; k < H; ++k) {
            float w = w0[t * H + k], ww = w * w;
            d  += ww * sa[k] * sl[k];
            na += ww * sa[k] * sa[k];
            nb += ww * sl[k] * sl[k];
        }
        orow[3 + t] = d / (fmaxf(sqrtf(na), EPSF) * fmaxf(sqrtf(nb), EPSF));
    } else if (t >= 32 && t < 32 + P) {        // amP: w2 vs att-mean
        int p = t - 32;
        float d = 0.f, na = 0.f, nb = 0.f;
        for (int k = 0; k < H; ++k) {
            float w = w2[p * H + k], ww = w * w;
            d  += ww * sa[k] * sam[k];
            na += ww * sa[k] * sa[k];
            nb += ww * sam[k] * sam[k];
        }
        orow[64 + p] = d / (fmaxf(sqrtf(na), EPSF) * fmaxf(sqrtf(nb), EPSF));
    } else if (t >= 64 && t < 64 + P) {        // axP: w3 vs att-max
        int p = t - 64;
        float d = 0.f, na = 0.f, nb = 0.f;
        for (int k = 0; k < H; ++k) {
            float w = w3[p * H + k], ww = w * w;
            d  += ww * sa[k] * sax[k];
            na += ww * sa[k] * sa[k];
            nb += ww * sax[k] * sax[k];
        }
        orow[85 + p] = d / (fmaxf(sqrtf(na), EPSF) * fmaxf(sqrtf(nb), EPSF));
    } else if (t >= 96 && t <= 98) {           // f1 / am1 / ax1 (unweighted)
        const float* o = (t == 96) ? sl : (t == 97) ? sam : sax;
        float d = 0.f, na = 0.f, nb = 0.f;
        for (int k = 0; k < H; ++k) {
            d  += sa[k] * o[k];
            na += sa[k] * sa[k];
            nb += o[k] * o[k];
        }
        float v = d / (fmaxf(sqrtf(na), EPSF) * fmaxf(sqrtf(nb), EPSF));
        orow[(t == 96) ? 2 : (t == 97) ? 63 : 84] = v;
    } else if (t == 99) {
        orow[0] = s_cosmax;
        orow[1] = s_cosmean;
    }
}

// ---------------------------------------------------------------- k_pair
// grid (L, B), block 128. One block per (b,i): u[p][k]=w1[p,k]^2*a[k] in LDS
// (float4, broadcast reads), thread j accumulates 20 dots over B-row j,
// LDS transpose (stride 129 breaks bank aliasing), threads 0..19 pool over j.
__global__ void k_pair(const float* __restrict__ A, const float* __restrict__ Bv,
                       const float* __restrict__ nwA, const float* __restrict__ nwB,
                       const int* __restrict__ maskA, const int* __restrict__ maskB,
                       const float* __restrict__ w1,
                       float* __restrict__ out)
{
    const int b = blockIdx.y, i = blockIdx.x, t = threadIdx.x;
    __shared__ float sa[H];
    __shared__ __align__(16) float su[P * H];
    __shared__ float snwA[P];
    __shared__ float smb[L];
    __shared__ float smv[P * 129];
    const float mA = (float)maskA[b * L + i];
    if (t < H) sa[t] = A[(b * L + i) * H + t];
    if (t < P) snwA[t] = nwA[(b * L + i) * P + t];
    smb[t] = mA * (float)maskB[b * L + t];
    __syncthreads();
    for (int idx = t; idx < P * H; idx += 128) {
        float w = w1[idx];
        su[idx] = w * w * sa[idx % H];
    }
    __syncthreads();

    const int j = t;  // blockDim == L
    float acc[P];
    #pragma unroll
    for (int p = 0; p < P; ++p) acc[p] = 0.f;
    const float4* bv4 = (const float4*)(Bv + (b * L + j) * H);
    const float4* su4 = (const float4*)su;
    for (int k4 = 0; k4 < H / 4; ++k4) {
        float4 v = bv4[k4];
        #pragma unroll
        for (int p = 0; p < P; ++p) {
            float4 u = su4[p * (H / 4) + k4];
            acc[p] += u.x * v.x + u.y * v.y + u.z * v.z + u.w * v.w;
        }
    }
    const float* nwBj = nwB + (b * L + j) * P;
    #pragma unroll
    for (int p = 0; p < P; ++p) {
        float mv = acc[p] / fmaxf(snwA[p] * nwBj[p], EPSF);
        smv[p * 129 + j] = mv;
    }
    __syncthreads();

    if (t < P) {
        float vmax = MINV, s = 0.f, cnt = 0.f, mm = 0.f;
        for (int j2 = 0; j2 < L; ++j2) {
            float mb = smb[j2];
            float v = smv[t * 129 + j2];
            if (mb > 0.f) vmax = fmaxf(vmax, v);
            s += v * mb;
            cnt += mb;
            mm = fmaxf(mm, mb);
        }
        float* orow = out + (b * L + i) * C;
        orow[23 + t] = vmax * mm;
        orow[43 + t] = s / fmaxf(cnt, EPSF);
    }
}

// ---------------------------------------------------------------- launch
extern "C" void kernel_launch(void* const* d_in, const int* in_sizes, int n_in,
                              void* d_out, int out_size, void* d_ws, size_t ws_size,
                              hipStream_t stream)
{
    const float* ctx_p = (const float*)d_in[0];
    const int*   mask_p = (const int*)d_in[1];
    const float* ctx_h = (const float*)d_in[2];
    const int*   mask_h = (const int*)d_in[3];
    const float* w0 = (const float*)d_in[4];
    const float* w1 = (const float*)d_in[5];
    const float* w2 = (const float*)d_in[6];
    const float* w3 = (const float*)d_in[7];
    float* out = (float*)d_out;

    // workspace carve-up (floats): total ~2.05M floats (~8.2 MB)
    float* ws   = (float*)d_ws;
    float* cp   = ws;                      // B*L*H
    float* ch   = cp   + B * L * H;        // B*L*H
    float* np_  = ch   + B * L * H;        // B*L
    float* nh_  = np_  + B * L;            // B*L
    float* nw1p = nh_  + B * L;            // B*L*P
    float* nw1h = nw1p + B * L * P;        // B*L*P
    float* cosM = nw1h + B * L * P;        // B*L*L
    float* cosT = cosM + B * L * L;        // B*L*L
    float* cpl  = cosT + B * L * L;        // B*H
    float* chl  = cpl  + B * H;            // B*H

    dim3 grid(L, B), blk(128);
    k_prep<<<grid, blk, 0, stream>>>(ctx_p, mask_p, w1, cp, np_, nw1p);
    k_prep<<<grid, blk, 0, stream>>>(ctx_h, mask_h, w1, ch, nh_, nw1h);
    k_last<<<dim3(B), blk, 0, stream>>>(mask_p, mask_h, cp, ch, cpl, chl);
    k_cos<<<grid, blk, 0, stream>>>(cp, ch, np_, nh_, cosM, cosT);

    // p side
    k_side<<<grid, blk, 0, stream>>>(cp, ch, cosM, mask_p, mask_h, chl,
                                     w0, w2, w3, out);
    k_pair<<<grid, blk, 0, stream>>>(cp, ch, nw1p, nw1h, mask_p, mask_h, w1, out);
    // h side
    float* out_h = out + B * L * C;
    k_side<<<grid, blk, 0, stream>>>(ch, cp, cosT, mask_h, mask_p, cpl,
                                     w0, w2, w3, out_h);
    k_pair<<<grid, blk, 0, stream>>>(ch, cp, nw1h, nw1p, mask_h, mask_p, w1, out_h);
}

// Round 2
// 198.732 us; speedup vs baseline: 1.9066x; 1.9066x over previous
//
#include <hip/hip_runtime.h>
#include <math.h>

// MatchingLayer (BiMPM-style) — MI355X. Round 2: MFMA k_pair + parallel k_side.
// B=32, L=128, H=100, P=20, C=105.

namespace {
constexpr int B = 32;
constexpr int L = 128;
constexpr int H = 100;
constexpr int P = 20;
constexpr int C = 105;
constexpr float EPSF = 1e-8f;
constexpr float MINV = -1e7f;
}

typedef unsigned short u16;
typedef unsigned int u32;
typedef short sh8 __attribute__((ext_vector_type(8)));   // 8 bf16 (4 VGPRs)
typedef float f4 __attribute__((ext_vector_type(4)));

__device__ __forceinline__ u16 f2bf(float f) {           // RNE f32->bf16
    u32 u = __float_as_uint(f);
    u += 0x7FFFu + ((u >> 16) & 1u);
    return (u16)(u >> 16);
}
__device__ __forceinline__ float bf2f(u32 h) {
    return __uint_as_float(h << 16);
}

// ---------------------------------------------------------------- k_wsq
// w1sq[p][k] = w1[p,k]^2, zero-padded to K=128.
__global__ void k_wsq(const float* __restrict__ w1, float* __restrict__ w1sq)
{
    const int p = blockIdx.x, t = threadIdx.x;
    float w = (t < H) ? w1[p * H + t] : 0.f;
    w1sq[p * 128 + t] = w * w;
}

// ---------------------------------------------------------------- k_prep
// masked vector (fp32 + bf16 K-padded copy), plain norm, P w1-weighted norms.
__global__ void k_prep(const float* __restrict__ ctx, const int* __restrict__ mask,
                       const float* __restrict__ w1,
                       float* __restrict__ dst, u16* __restrict__ dstb,
                       float* __restrict__ nrm, float* __restrict__ nw)
{
    const int b = blockIdx.y, i = blockIdx.x, t = threadIdx.x;
    const int row = b * L + i;
    __shared__ float sv2[H];
    const float m = (float)mask[row];
    float v = 0.f;
    if (t < H) {
        v = ctx[row * H + t] * m;
        dst[row * H + t] = v;
        sv2[t] = v * v;
    }
    dstb[row * 128 + t] = f2bf(v);   // v==0 for t>=H -> zero pad
    __syncthreads();
    if (t < P) {
        float acc = 0.f;
        #pragma unroll 4
        for (int k = 0; k < H; ++k) { float w = w1[t * H + k]; acc += w * w * sv2[k]; }
        nw[row * P + t] = sqrtf(acc);
    } else if (t == P) {
        float acc = 0.f;
        for (int k = 0; k < H; ++k) acc += sv2[k];
        nrm[row] = sqrtf(acc);
    }
}

// ---------------------------------------------------------------- k_last
__global__ void k_last(const int* __restrict__ mask_p, const int* __restrict__ mask_h,
                       const float* __restrict__ cp, const float* __restrict__ ch,
                       float* __restrict__ cpl, float* __restrict__ chl)
{
    const int b = blockIdx.x, t = threadIdx.x;
    __shared__ int sidx[2];
    if (t == 0) {
        int s = 0;
        for (int j = 0; j < L; ++j) s += mask_p[b * L + j];
        sidx[0] = (s - 1 > 0) ? (s - 1) : 0;
        s = 0;
        for (int j = 0; j < L; ++j) s += mask_h[b * L + j];
        sidx[1] = (s - 1 > 0) ? (s - 1) : 0;
    }
    __syncthreads();
    if (t < H) {
        cpl[b * H + t] = cp[(b * L + sidx[0]) * H + t];
        chl[b * H + t] = ch[(b * L + sidx[1]) * H + t];
    }
}

// ---------------------------------------------------------------- k_cos
__global__ void k_cos(const float* __restrict__ cp, const float* __restrict__ ch,
                      const float* __restrict__ np_, const float* __restrict__ nh_,
                      float* __restrict__ cosM)
{
    const int b = blockIdx.y, i = blockIdx.x, t = threadIdx.x;
    __shared__ __align__(16) float sa[H];
    if (t < H) sa[t] = cp[(b * L + i) * H + t];
    __syncthreads();
    const float4* a4 = (const float4*)sa;
    const float4* bv4 = (const float4*)(ch + (b * L + t) * H);
    float dot = 0.f;
    #pragma unroll
    for (int k = 0; k < H / 4; ++k) {
        float4 a = a4[k], v = bv4[k];
        dot += a.x * v.x + a.y * v.y + a.z * v.z + a.w * v.w;
    }
    cosM[(b * L + i) * L + t] = dot / fmaxf(np_[b * L + i] * nh_[b * L + t], EPSF);
}

// ---------------------------------------------------------------- k_side
// block 256. Wave-mapped epilogues, parallel reductions, float4 dots.
__global__ __launch_bounds__(256) void
k_side(const float* __restrict__ A, const float* __restrict__ Bv,
       const float* __restrict__ cosM, const int transposed,
       const int* __restrict__ maskA, const int* __restrict__ maskB,
       const float* __restrict__ lastV,
       const float* __restrict__ w0, const float* __restrict__ w2,
       const float* __restrict__ w3, float* __restrict__ out)
{
    const int b = blockIdx.y, i = blockIdx.x, t = threadIdx.x;
    __shared__ __align__(16) float sa[H], sl[H], sam[H], sax[H];
    __shared__ float scos[L], smb[L];
    __shared__ float pam[2][H], pax[2][H];
    __shared__ float s_scal[4];   // sumcos, mmax, cosmax, cosmean
    const float mA = (float)maskA[b * L + i];
    if (t < H) { sa[t] = A[(b * L + i) * H + t]; sl[t] = lastV[b * H + t]; }
    if (t < L) {
        scos[t] = transposed ? cosM[(b * L + t) * L + i] : cosM[(b * L + i) * L + t];
        smb[t] = mA * (float)maskB[b * L + t];
    }
    __syncthreads();

    if (t < 64) {  // wave0: block-wide scalars
        float c0 = scos[t], c1 = scos[t + 64];
        float b0 = smb[t], b1 = smb[t + 64];
        float sc = c0 + c1;
        float sm = c0 * b0 + c1 * b1;
        float cn = b0 + b1;
        float mm = fmaxf(b0, b1);
        float vm = fmaxf(b0 > 0.f ? c0 : MINV, b1 > 0.f ? c1 : MINV);
        for (int d = 1; d < 64; d <<= 1) {
            sc += __shfl_xor(sc, d);
            sm += __shfl_xor(sm, d);
            cn += __shfl_xor(cn, d);
            mm = fmaxf(mm, __shfl_xor(mm, d));
            vm = fmaxf(vm, __shfl_xor(vm, d));
        }
        if (t == 0) {
            s_scal[0] = sc; s_scal[1] = mm;
            s_scal[2] = vm * mm;
            s_scal[3] = sm / fmaxf(cn, EPSF);
        }
    }
    // attentive partials: group 0 -> j in [0,64), group 1 -> [64,128)
    {
        const int g = t >> 7, tt = t & 127;
        if (tt < H) {
            float am = 0.f, ax = MINV;
            const int j0 = g * 64;
            for (int j = j0; j < j0 + 64; ++j) {
                float bv = Bv[(b * L + j) * H + tt];
                float v = scos[j] * bv;
                am += v;
                ax = fmaxf(ax, smb[j] > 0.f ? v : MINV);
            }
            pam[g][tt] = am; pax[g][tt] = ax;
        }
    }
    __syncthreads();
    if (t < H) {
        sam[t] = (pam[0][t] + pam[1][t]) / fmaxf(s_scal[0], EPSF);
        sax[t] = fmaxf(pax[0][t], pax[1][t]) * s_scal[1];
    }
    __syncthreads();

    float* orow = out + (b * L + i) * C;
    const int wv = t >> 6, ln = t & 63;
    if (wv < 3) {
        if (ln < P) {
            const float* wmat = (wv == 0) ? w0 : (wv == 1) ? w2 : w3;
            const float* oth  = (wv == 0) ? sl : (wv == 1) ? sam : sax;
            const float4* w4 = (const float4*)(wmat + ln * H);
            const float4* a4 = (const float4*)sa;
            const float4* o4 = (const float4*)oth;
            float d = 0.f, na = 0.f, nb = 0.f;
            #pragma unroll 5
            for (int k = 0; k < H / 4; ++k) {
                float4 w = w4[k], a = a4[k], o = o4[k];
                float ww;
                ww = w.x * w.x; d += ww * a.x * o.x; na += ww * a.x * a.x; nb += ww * o.x * o.x;
                ww = w.y * w.y; d += ww * a.y * o.y; na += ww * a.y * a.y; nb += ww * o.y * o.y;
                ww = w.z * w.z; d += ww * a.z * o.z; na += ww * a.z * a.z; nb += ww * o.z * o.z;
                ww = w.w * w.w; d += ww * a.w * o.w; na += ww * a.w * a.w; nb += ww * o.w * o.w;
            }
            const int base = (wv == 0) ? 3 : (wv == 1) ? 64 : 85;
            orow[base + ln] = d / (fmaxf(sqrtf(na), EPSF) * fmaxf(sqrtf(nb), EPSF));
        }
    } else {
        if (ln < 3) {
            const float* oth = (ln == 0) ? sl : (ln == 1) ? sam : sax;
            const float4* a4 = (const float4*)sa;
            const float4* o4 = (const float4*)oth;
            float d = 0.f, na = 0.f, nb = 0.f;
            #pragma unroll 5
            for (int k = 0; k < H / 4; ++k) {
                float4 a = a4[k], o = o4[k];
                d += a.x * o.x + a.y * o.y + a.z * o.z + a.w * o.w;
                na += a.x * a.x + a.y * a.y + a.z * a.z + a.w * a.w;
                nb += o.x * o.x + o.y * o.y + o.z * o.z + o.w * o.w;
            }
            orow[(ln == 0) ? 2 : (ln == 1) ? 63 : 84] =
                d / (fmaxf(sqrtf(na), EPSF) * fmaxf(sqrtf(nb), EPSF));
        } else if (ln == 3) {
            orow[0] = s_scal[2];
            orow[1] = s_scal[3];
        }
    }
}

// ---------------------------------------------------------------- k_pair_mfma
// One block per (b,p); 4 waves; 128x128x128(bf16) MFMA GEMM; in-register
// masked max/mean pooling over BOTH axes (writes p-side and h-side channels).
__global__ __launch_bounds__(256) void
k_pair_mfma(const u16* __restrict__ Ab, const u16* __restrict__ Bb,
            const float* __restrict__ w1sq,
            const float* __restrict__ nwA, const float* __restrict__ nwB,
            const int* __restrict__ maskA, const int* __restrict__ maskB,
            float* __restrict__ outP, float* __restrict__ outH)
{
    const int p = blockIdx.x, b = blockIdx.y, t = threadIdx.x;
    __shared__ __align__(16) u16 sB[128 * 136];       // +8 bf16 pad: 2-way banks
    __shared__ float snwA[128], snwB[128], smA[128], smB[128];
    __shared__ float pJmax[128], pJsum[128];
    __shared__ float pImax[4][128], pIsum[4][128];
    __shared__ float sRed[4];                          // maxA,sumA,maxB,sumB

    if (t < 128) {
        snwA[t] = nwA[(b * L + t) * P + p];
        snwB[t] = nwB[(b * L + t) * P + p];
        smA[t] = (float)maskA[b * L + t];
        smB[t] = (float)maskB[b * L + t];
    }
    __syncthreads();

    // mask scalar reductions (waves 0/1)
    if (t < 64) {
        float a0 = smB[t], a1 = smB[t + 64];
        float mx = fmaxf(a0, a1), sm = a0 + a1;
        for (int d = 1; d < 64; d <<= 1) {
            mx = fmaxf(mx, __shfl_xor(mx, d));
            sm += __shfl_xor(sm, d);
        }
        if (t == 0) { sRed[2] = mx; sRed[3] = sm; }
    } else if (t < 128) {
        const int l = t - 64;
        float a0 = smA[l], a1 = smA[l + 64];
        float mx = fmaxf(a0, a1), sm = a0 + a1;
        for (int d = 1; d < 64; d <<= 1) {
            mx = fmaxf(mx, __shfl_xor(mx, d));
            sm += __shfl_xor(sm, d);
        }
        if (l == 0) { sRed[0] = mx; sRed[1] = sm; }
    }

    // stage B into LDS (straight bf16 copy, K already zero-padded)
    {
        const uint4* src = (const uint4*)(Bb + (size_t)b * L * 128);
        #pragma unroll
        for (int it = 0; it < 8; ++it) {
            int idx = it * 256 + t;
            int row = idx >> 4, kc = (idx & 15) * 8;
            uint4 v = src[idx];
            *(uint4*)&sB[row * 136 + kc] = v;
        }
    }
    __syncthreads();

    const int wave = t >> 6, lane = t & 63;
    const int m = lane & 15, q = lane >> 4;

    // preload w1sq slices for this lane's k positions: k = ks*32 + q*8 + [0,8)
    float4 swv[4][2];
    #pragma unroll
    for (int ks = 0; ks < 4; ++ks) {
        const float* wp = w1sq + p * 128 + ks * 32 + q * 8;
        swv[ks][0] = *(const float4*)wp;
        swv[ks][1] = *(const float4*)(wp + 4);
    }

    f4 acc[2][8];
    #pragma unroll
    for (int rt = 0; rt < 2; ++rt)
        #pragma unroll
        for (int ct = 0; ct < 8; ++ct)
            acc[rt][ct] = (f4){0.f, 0.f, 0.f, 0.f};

    const uint4* gA0 = (const uint4*)(Ab + (size_t)(b * L + wave * 32 + m) * 128);
    const uint4* gA1 = (const uint4*)(Ab + (size_t)(b * L + wave * 32 + 16 + m) * 128);

    #pragma unroll
    for (int ks = 0; ks < 4; ++ks) {
        uint4 va0 = gA0[ks * 4 + q];
        uint4 va1 = gA1[ks * 4 + q];
        // weight + round to bf16 fragments
        sh8 a0, a1;
        {
            u32 vs0[4] = {va0.x, va0.y, va0.z, va0.w};
            u32 vs1[4] = {va1.x, va1.y, va1.z, va1.w};
            float wv[8] = {swv[ks][0].x, swv[ks][0].y, swv[ks][0].z, swv[ks][0].w,
                           swv[ks][1].x, swv[ks][1].y, swv[ks][1].z, swv[ks][1].w};
            u32 r0[4], r1[4];
            #pragma unroll
            for (int e = 0; e < 4; ++e) {
                float f0 = bf2f(vs0[e] & 0xffffu) * wv[2 * e];
                float f1 = bf2f(vs0[e] >> 16) * wv[2 * e + 1];
                r0[e] = (u32)f2bf(f0) | ((u32)f2bf(f1) << 16);
                float g0 = bf2f(vs1[e] & 0xffffu) * wv[2 * e];
                float g1 = bf2f(vs1[e] >> 16) * wv[2 * e + 1];
                r1[e] = (u32)f2bf(g0) | ((u32)f2bf(g1) << 16);
            }
            uint4 o0 = {r0[0], r0[1], r0[2], r0[3]};
            uint4 o1 = {r1[0], r1[1], r1[2], r1[3]};
            a0 = __builtin_bit_cast(sh8, o0);
            a1 = __builtin_bit_cast(sh8, o1);
        }
        const int ko = ks * 32 + q * 8;
        #pragma unroll
        for (int ct = 0; ct < 8; ++ct) {
            sh8 bb = *(const sh8*)&sB[(ct * 16 + m) * 136 + ko];
            acc[0][ct] = __builtin_amdgcn_mfma_f32_16x16x32_bf16(a0, bb, acc[0][ct], 0, 0, 0);
            acc[1][ct] = __builtin_amdgcn_mfma_f32_16x16x32_bf16(a1, bb, acc[1][ct], 0, 0, 0);
        }
    }

    // ------- epilogue: mv = acc / max(nwA*nwB, eps); pool over j and i -------
    float nB[8], mBv[8], imax[8], isum[8];
    #pragma unroll
    for (int ct = 0; ct < 8; ++ct) {
        const int j = ct * 16 + m;
        nB[ct] = snwB[j]; mBv[ct] = smB[j];
        imax[ct] = MINV; isum[ct] = 0.f;
    }
    #pragma unroll
    for (int rt = 0; rt < 2; ++rt) {
        #pragma unroll
        for (int reg = 0; reg < 4; ++reg) {
            const int i = wave * 32 + rt * 16 + q * 4 + reg;
            const float na = snwA[i];
            const float ma = smA[i];
            float jmax = MINV, jsum = 0.f;
            #pragma unroll
            for (int ct = 0; ct < 8; ++ct) {
                float v = acc[rt][ct][reg] *
                          __builtin_amdgcn_rcpf(fmaxf(na * nB[ct], EPSF));
                jmax = fmaxf(jmax, mBv[ct] > 0.f ? v : MINV);
                jsum += mBv[ct] > 0.f ? v : 0.f;
                imax[ct] = fmaxf(imax[ct], ma > 0.f ? v : MINV);
                isum[ct] += ma > 0.f ? v : 0.f;
            }
            for (int d = 1; d < 16; d <<= 1) {
                jmax = fmaxf(jmax, __shfl_xor(jmax, d));
                jsum += __shfl_xor(jsum, d);
            }
            if (m == 0) { pJmax[i] = jmax; pJsum[i] = jsum; }
        }
    }
    #pragma unroll
    for (int ct = 0; ct < 8; ++ct) {
        float mx = imax[ct], sm = isum[ct];
        mx = fmaxf(mx, __shfl_xor(mx, 16)); sm += __shfl_xor(sm, 16);
        mx = fmaxf(mx, __shfl_xor(mx, 32)); sm += __shfl_xor(sm, 32);
        if (q == 0) { const int j = ct * 16 + m; pImax[wave][j] = mx; pIsum[wave][j] = sm; }
    }
    __syncthreads();

    if (t < 128) {
        const int i = t;
        const float ma = smA[i];
        const float mm = ma * sRed[2];     // * maxB
        const float cnt = ma * sRed[3];    // * sumB
        float* orow = outP + (b * L + i) * C;
        orow[23 + p] = pJmax[i] * mm;
        orow[43 + p] = ma * pJsum[i] / fmaxf(cnt, EPSF);

        const float mb = smB[i];
        const float hmax = fmaxf(fmaxf(pImax[0][i], pImax[1][i]),
                                 fmaxf(pImax[2][i], pImax[3][i]));
        const float hsum = pIsum[0][i] + pIsum[1][i] + pIsum[2][i] + pIsum[3][i];
        float* hrow = outH + (b * L + i) * C;
        hrow[23 + p] = hmax * mb * sRed[0];
        hrow[43 + p] = mb * hsum / fmaxf(mb * sRed[1], EPSF);
    }
}

// ---------------------------------------------------------------- launch
extern "C" void kernel_launch(void* const* d_in, const int* in_sizes, int n_in,
                              void* d_out, int out_size, void* d_ws, size_t ws_size,
                              hipStream_t stream)
{
    const float* ctx_p = (const float*)d_in[0];
    const int*   mask_p = (const int*)d_in[1];
    const float* ctx_h = (const float*)d_in[2];
    const int*   mask_h = (const int*)d_in[3];
    const float* w0 = (const float*)d_in[4];
    const float* w1 = (const float*)d_in[5];
    const float* w2 = (const float*)d_in[6];
    const float* w3 = (const float*)d_in[7];
    float* out = (float*)d_out;

    float* ws   = (float*)d_ws;
    float* cp   = ws;                       // B*L*H   = 409600
    float* ch   = cp   + B * L * H;         // 409600
    float* np_  = ch   + B * L * H;         // B*L = 4096
    float* nh_  = np_  + B * L;
    float* nw1p = nh_  + B * L;             // B*L*P = 81920
    float* nw1h = nw1p + B * L * P;
    float* cosM = nw1h + B * L * P;         // B*L*L = 524288
    float* cpl  = cosM + B * L * L;         // B*H = 3200
    float* chl  = cpl  + B * H;
    float* w1sq = chl  + B * H;             // P*128 = 2560
    u16*   cpb  = (u16*)(w1sq + P * 128);   // B*L*128 u16 = 262144 floats
    u16*   chb  = cpb + B * L * 128;

    dim3 grid(L, B), blk(128);
    k_wsq<<<dim3(P), blk, 0, stream>>>(w1, w1sq);
    k_prep<<<grid, blk, 0, stream>>>(ctx_p, mask_p, w1, cp, cpb, np_, nw1p);
    k_prep<<<grid, blk, 0, stream>>>(ctx_h, mask_h, w1, ch, chb, nh_, nw1h);
    k_last<<<dim3(B), blk, 0, stream>>>(mask_p, mask_h, cp, ch, cpl, chl);
    k_cos<<<grid, blk, 0, stream>>>(cp, ch, np_, nh_, cosM);

    float* out_h = out + B * L * C;
    k_side<<<grid, dim3(256), 0, stream>>>(cp, ch, cosM, 0, mask_p, mask_h, chl,
                                           w0, w2, w3, out);
    k_side<<<grid, dim3(256), 0, stream>>>(ch, cp, cosM, 1, mask_h, mask_p, cpl,
                                           w0, w2, w3, out_h);
    k_pair_mfma<<<dim3(P, B), dim3(256), 0, stream>>>(cpb, chb, w1sq, nw1p, nw1h,
                                                      mask_p, mask_h, out, out_h);
}